// Round 1
// 383.410 us; speedup vs baseline: 1.1166x; 1.1166x over previous
//
#include <hip/hip_runtime.h>
#include <hip/hip_bf16.h>

#define T 128
#define F 64
#define H1 32
#define G1 128   // 4*H1
#define H2 16
#define G2 64    // 4*H2

typedef __attribute__((ext_vector_type(8))) short bf16x8;
typedef __attribute__((ext_vector_type(4))) float f32x4;

// Native-rate activations: v_exp + v_rcp (1-ulp class). Error is far below
// the bf16 rounding of h, so end-to-end tolerance is unaffected.
__device__ __forceinline__ float sigmoidf_(float x) {
    return __builtin_amdgcn_rcpf(1.0f + __expf(-x));
}
__device__ __forceinline__ float tanhf_(float x) {
    return 1.0f - 2.0f * __builtin_amdgcn_rcpf(__expf(2.0f * x) + 1.0f);
}
__device__ __forceinline__ unsigned short f2bf(float f) {
    union { float f; unsigned u; } c; c.f = f;
    unsigned r = c.u + 0x7FFF + ((c.u >> 16) & 1);   // RTNE
    return (unsigned short)(r >> 16);
}
// LDS-only barrier: waits DS ops, does NOT drain vmcnt (global prefetches
// stay in flight across the per-step sync).
__device__ __forceinline__ void lds_barrier() {
    asm volatile("s_waitcnt lgkmcnt(0)" ::: "memory");
    __builtin_amdgcn_s_barrier();
}

// =============================================================================
// K0: convert x fp32 -> bf16 in A-fragment-packed layout, via LDS transpose.
// Packed layout per (g,t), 1024 shorts: value (sample m, col k) at
//   slot = (k>>5)*512 + (m + 16*((k&31)>>3))*8 + (k&7)
// LSTM lane then loads bf16x8 at ks*512 + lane*8 — one b128, coalesced.
// =============================================================================
__global__ __launch_bounds__(256) void xcvt(
    const float* __restrict__ x,          // [B][T][64]
    unsigned short* __restrict__ xbf)
{
    __shared__ unsigned short tile[1024];
    const int g  = blockIdx.x;
    const int t0 = blockIdx.y * 8;
    const int m  = threadIdx.x >> 4;      // sample in group
    const int c4 = threadIdx.x & 15;      // float4 index in row
    const int ks   = c4 >> 3;
    const int quad = (c4 & 7) >> 1;
    const int j0   = (c4 & 1) * 4;
    const int slot = ks * 512 + (m + 16 * quad) * 8 + j0;

    for (int tt = 0; tt < 8; ++tt) {
        const int t = t0 + tt;
        const float4 v = *(const float4*)(x + ((size_t)(g * 16 + m) * T + t) * 64 + c4 * 4);
        ushort4 u;
        u.x = f2bf(v.x); u.y = f2bf(v.y); u.z = f2bf(v.z); u.w = f2bf(v.w);
        *(ushort4*)(tile + slot) = u;
        __syncthreads();
        // coalesced: 256 threads x 8 B = one contiguous 2 KB burst
        *(uint2*)(xbf + (size_t)(g * T + t) * 1024 + threadIdx.x * 4) =
            *(const uint2*)(tile + threadIdx.x * 4);
        __syncthreads();
    }
}

// =============================================================================
// K1: layer-1 recurrence with fused x@W1. Block = (g, d), 4 waves:
// wave = (gate-half gh = wv&1, sample-half sh = wv>>1). Software-pipelined:
// xa[4] = bias + x(t)*W is built ONE STEP AHEAD, so the barrier-to-barrier
// critical path is ds_read(h) -> 1 U-MFMA -> activation. The 8 xa-rebuild
// MFMAs for step s+2 issue under the activation VALU (separate pipe).
// =============================================================================
__global__ __launch_bounds__(256, 2) void lstm1_fused(
    const unsigned short* __restrict__ xbf,
    const float* __restrict__ W1f, const float* __restrict__ b1f, const float* __restrict__ U1f,
    const float* __restrict__ W1b, const float* __restrict__ b1b, const float* __restrict__ U1b,
    unsigned short* __restrict__ h1)     // packed per (g,t), 1024 shorts
{
    __shared__ unsigned short hb[2][16 * 40];
    const int tid  = threadIdx.x;
    const int lane = tid & 63;
    const int wv   = __builtin_amdgcn_readfirstlane(tid >> 6);
    const int gh   = wv & 1;
    const int sh   = wv >> 1;            // 0..1
    const int n15  = lane & 15, quad = lane >> 4;
    const int d    = blockIdx.x & 1, g = blockIdx.x >> 1;

    const float* W  = d ? W1b : W1f;
    const float* U  = d ? U1b : U1f;
    const float* bs = d ? b1b : b1f;

    // frag q = 2*i + gh covers gate cols q*16+n15 (i,f,g,o co-located per col)
    bf16x8 Wf[4][2], Uf[4];
    f32x4 biasC[4];
    #pragma unroll
    for (int i = 0; i < 4; ++i) {
        const int col = (2 * i + gh) * 16 + n15;
        biasC[i] = (f32x4)(bs[col]);
        #pragma unroll
        for (int ks = 0; ks < 2; ++ks) {
            bf16x8 f;
            #pragma unroll
            for (int j = 0; j < 8; ++j)
                f[j] = (short)f2bf(W[(ks * 32 + quad * 8 + j) * G1 + col]);
            Wf[i][ks] = f;
        }
        bf16x8 u;
        #pragma unroll
        for (int j = 0; j < 8; ++j)
            u[j] = (short)f2bf(U[(quad * 8 + j) * G1 + col]);
        Uf[i] = u;
    }

    // zero h(-1) buffer + pads (1280 shorts total)
    #pragma unroll
    for (int i = 0; i < 5; ++i) ((unsigned short*)hb)[tid + i * 256] = 0;

    float c0 = 0.0f, c1 = 0.0f;
    const unsigned short* xb = xbf + (size_t)g * T * 1024 + lane * 8;
    // packed h1 slots for this lane's two samples (m = quad*4+2*sh+{0,1})
    unsigned short* h1b0 = h1 + (size_t)g * T * 1024
        + d * 512 + ((quad * 4 + 2 * sh) + 16 * (gh * 2 + (n15 >> 3))) * 8 + (n15 & 7);
    unsigned short* h1b1 = h1b0 + 8;

    // ---- prologue: xa for steps 0 and 1; prefetch x for steps 2 and 3 ----
    f32x4 xaA[4], xaB[4];
    bf16x8 xA0, xA1, xB0, xB1;
    {
        const unsigned short* p0 = xb + (size_t)(d ? (T - 1) : 0) * 1024;
        bf16x8 t0 = *(const bf16x8*)(p0), t1 = *(const bf16x8*)(p0 + 512);
        #pragma unroll
        for (int i = 0; i < 4; ++i) {
            xaA[i] = __builtin_amdgcn_mfma_f32_16x16x32_bf16(t0, Wf[i][0], biasC[i], 0, 0, 0);
            xaA[i] = __builtin_amdgcn_mfma_f32_16x16x32_bf16(t1, Wf[i][1], xaA[i], 0, 0, 0);
        }
        const unsigned short* p1 = xb + (size_t)(d ? (T - 2) : 1) * 1024;
        t0 = *(const bf16x8*)(p1); t1 = *(const bf16x8*)(p1 + 512);
        #pragma unroll
        for (int i = 0; i < 4; ++i) {
            xaB[i] = __builtin_amdgcn_mfma_f32_16x16x32_bf16(t0, Wf[i][0], biasC[i], 0, 0, 0);
            xaB[i] = __builtin_amdgcn_mfma_f32_16x16x32_bf16(t1, Wf[i][1], xaB[i], 0, 0, 0);
        }
        const unsigned short* p2 = xb + (size_t)(d ? (T - 3) : 2) * 1024;
        xA0 = *(const bf16x8*)(p2); xA1 = *(const bf16x8*)(p2 + 512);
        const unsigned short* p3 = xb + (size_t)(d ? (T - 4) : 3) * 1024;
        xB0 = *(const bf16x8*)(p3); xB1 = *(const bf16x8*)(p3 + 512);
    }
    lds_barrier();

    auto step = [&](int s, f32x4* xa, bf16x8& x0, bf16x8& x1) {
        // post-barrier critical path: one ds_read + one MFMA depth
        const bf16x8 af = *(const bf16x8*)(hb[s & 1] + n15 * 40 + quad * 8);
        f32x4 a0 = __builtin_amdgcn_mfma_f32_16x16x32_bf16(af, Uf[0], xa[0], 0, 0, 0);
        f32x4 a1 = __builtin_amdgcn_mfma_f32_16x16x32_bf16(af, Uf[1], xa[1], 0, 0, 0);
        f32x4 a2 = __builtin_amdgcn_mfma_f32_16x16x32_bf16(af, Uf[2], xa[2], 0, 0, 0);
        f32x4 a3 = __builtin_amdgcn_mfma_f32_16x16x32_bf16(af, Uf[3], xa[3], 0, 0, 0);

        // rebuild xa for step s+2 (independent; overlaps activation VALU)
        xa[0] = __builtin_amdgcn_mfma_f32_16x16x32_bf16(x0, Wf[0][0], biasC[0], 0, 0, 0);
        xa[1] = __builtin_amdgcn_mfma_f32_16x16x32_bf16(x0, Wf[1][0], biasC[1], 0, 0, 0);
        xa[2] = __builtin_amdgcn_mfma_f32_16x16x32_bf16(x0, Wf[2][0], biasC[2], 0, 0, 0);
        xa[3] = __builtin_amdgcn_mfma_f32_16x16x32_bf16(x0, Wf[3][0], biasC[3], 0, 0, 0);
        xa[0] = __builtin_amdgcn_mfma_f32_16x16x32_bf16(x1, Wf[0][1], xa[0], 0, 0, 0);
        xa[1] = __builtin_amdgcn_mfma_f32_16x16x32_bf16(x1, Wf[1][1], xa[1], 0, 0, 0);
        xa[2] = __builtin_amdgcn_mfma_f32_16x16x32_bf16(x1, Wf[2][1], xa[2], 0, 0, 0);
        xa[3] = __builtin_amdgcn_mfma_f32_16x16x32_bf16(x1, Wf[3][1], xa[3], 0, 0, 0);

        // prefetch x for step s+4 (2-step lead covers HBM latency)
        if (s + 4 < T) {
            const unsigned short* pn = xb + (size_t)(d ? (T - 5 - s) : (s + 4)) * 1024;
            x0 = *(const bf16x8*)(pn); x1 = *(const bf16x8*)(pn + 512);
        }

        const int t = d ? (T - 1 - s) : s;
        // wave-uniform row select (sh is in SGPR -> uniform branch, no cndmask)
        float zi0, zi1, zf0, zf1, zg0, zg1, zo0, zo1;
        if (sh == 0) {
            zi0 = a0[0]; zi1 = a0[1]; zf0 = a1[0]; zf1 = a1[1];
            zg0 = a2[0]; zg1 = a2[1]; zo0 = a3[0]; zo1 = a3[1];
        } else {
            zi0 = a0[2]; zi1 = a0[3]; zf0 = a1[2]; zf1 = a1[3];
            zg0 = a2[2]; zg1 = a2[3]; zo0 = a3[2]; zo1 = a3[3];
        }
        {   // update 0: sample quad*4 + 2*sh
            const float ig = sigmoidf_(zi0);
            const float fg = sigmoidf_(zf0);
            const float gg = tanhf_(zg0);
            const float og = sigmoidf_(zo0);
            c0 = fg * c0 + ig * gg;
            const float h = og * tanhf_(c0);
            const unsigned short us = f2bf(h);
            hb[(s + 1) & 1][(quad * 4 + 2 * sh) * 40 + gh * 16 + n15] = us;
            h1b0[(size_t)t * 1024] = us;
        }
        {   // update 1: sample quad*4 + 2*sh + 1
            const float ig = sigmoidf_(zi1);
            const float fg = sigmoidf_(zf1);
            const float gg = tanhf_(zg1);
            const float og = sigmoidf_(zo1);
            c1 = fg * c1 + ig * gg;
            const float h = og * tanhf_(c1);
            const unsigned short us = f2bf(h);
            hb[(s + 1) & 1][(quad * 4 + 2 * sh + 1) * 40 + gh * 16 + n15] = us;
            h1b1[(size_t)t * 1024] = us;
        }
        lds_barrier();
    };

    #pragma unroll 1
    for (int s = 0; s < T; s += 2) {
        step(s, xaA, xA0, xA1);
        step(s + 1, xaB, xB0, xB1);
    }
}

// =============================================================================
// K2: layer-2 recurrence with fused h1@W2 (K=64) + U2 (K=16 zero-padded) +
// dense head. Block = g, 8 waves: (d = wv&1, sh = wv>>1). Same software
// pipeline as K1: xa built one step ahead, 1-MFMA post-barrier depth.
// =============================================================================
__global__ __launch_bounds__(512, 2) void lstm2_head(
    const unsigned short* __restrict__ h1,
    const float* __restrict__ W2f, const float* __restrict__ b2f, const float* __restrict__ U2f,
    const float* __restrict__ W2b, const float* __restrict__ b2b, const float* __restrict__ U2b,
    const float* __restrict__ W3, const float* __restrict__ b3,
    const float* __restrict__ W4, const float* __restrict__ b4,
    float* __restrict__ out)             // [B][2]
{
    __shared__ unsigned short hb2[2][2][400];   // [d][buf], stride 24, padded
    __shared__ float hfin[2][16][16];
    __shared__ float ybuf[16][9];
    const int tid  = threadIdx.x;
    const int lane = tid & 63;
    const int wv   = __builtin_amdgcn_readfirstlane(tid >> 6);
    const int d    = wv & 1;
    const int sh   = wv >> 1;            // 0..3
    const int n15  = lane & 15, quad = lane >> 4;
    const int g    = blockIdx.x;

    const float* W  = d ? W2b : W2f;
    const float* U  = d ? U2b : U2f;
    const float* bs = d ? b2b : b2f;

    bf16x8 Wf[4][2], Uf[4];
    f32x4 biasC[4];
    #pragma unroll
    for (int i = 0; i < 4; ++i) {
        const int col = i * 16 + n15;
        biasC[i] = (f32x4)(bs[col]);
        #pragma unroll
        for (int ks = 0; ks < 2; ++ks) {
            bf16x8 f;
            #pragma unroll
            for (int j = 0; j < 8; ++j)
                f[j] = (short)f2bf(W[(ks * 32 + quad * 8 + j) * G2 + col]);
            Wf[i][ks] = f;
        }
        bf16x8 u;
        #pragma unroll
        for (int j = 0; j < 8; ++j) {
            const int k = quad * 8 + j;
            u[j] = (k < H2) ? (short)f2bf(U[k * G2 + col]) : (short)0;
        }
        Uf[i] = u;
    }

    #pragma unroll
    for (int i = 0; i < 4; ++i) {
        const int idx = tid + i * 512;
        if (idx < 1600) ((unsigned short*)hb2)[idx] = 0;
    }

    float c = 0.0f, hlast = 0.0f;
    const unsigned short* hl = h1 + (size_t)g * T * 1024 + lane * 8;

    f32x4 xaA[4], xaB[4];
    bf16x8 hA0, hA1, hB0, hB1;
    {
        const unsigned short* p0 = hl + (size_t)(d ? (T - 1) : 0) * 1024;
        bf16x8 t0 = *(const bf16x8*)(p0), t1 = *(const bf16x8*)(p0 + 512);
        #pragma unroll
        for (int i = 0; i < 4; ++i) {
            xaA[i] = __builtin_amdgcn_mfma_f32_16x16x32_bf16(t0, Wf[i][0], biasC[i], 0, 0, 0);
            xaA[i] = __builtin_amdgcn_mfma_f32_16x16x32_bf16(t1, Wf[i][1], xaA[i], 0, 0, 0);
        }
        const unsigned short* p1 = hl + (size_t)(d ? (T - 2) : 1) * 1024;
        t0 = *(const bf16x8*)(p1); t1 = *(const bf16x8*)(p1 + 512);
        #pragma unroll
        for (int i = 0; i < 4; ++i) {
            xaB[i] = __builtin_amdgcn_mfma_f32_16x16x32_bf16(t0, Wf[i][0], biasC[i], 0, 0, 0);
            xaB[i] = __builtin_amdgcn_mfma_f32_16x16x32_bf16(t1, Wf[i][1], xaB[i], 0, 0, 0);
        }
        const unsigned short* p2 = hl + (size_t)(d ? (T - 3) : 2) * 1024;
        hA0 = *(const bf16x8*)(p2); hA1 = *(const bf16x8*)(p2 + 512);
        const unsigned short* p3 = hl + (size_t)(d ? (T - 4) : 3) * 1024;
        hB0 = *(const bf16x8*)(p3); hB1 = *(const bf16x8*)(p3 + 512);
    }
    lds_barrier();

    auto step = [&](int s, f32x4* xa, bf16x8& x0, bf16x8& x1) {
        const bf16x8 af = *(const bf16x8*)(hb2[d][s & 1] + n15 * 24 + quad * 8);
        f32x4 a0 = __builtin_amdgcn_mfma_f32_16x16x32_bf16(af, Uf[0], xa[0], 0, 0, 0);
        f32x4 a1 = __builtin_amdgcn_mfma_f32_16x16x32_bf16(af, Uf[1], xa[1], 0, 0, 0);
        f32x4 a2 = __builtin_amdgcn_mfma_f32_16x16x32_bf16(af, Uf[2], xa[2], 0, 0, 0);
        f32x4 a3 = __builtin_amdgcn_mfma_f32_16x16x32_bf16(af, Uf[3], xa[3], 0, 0, 0);

        xa[0] = __builtin_amdgcn_mfma_f32_16x16x32_bf16(x0, Wf[0][0], biasC[0], 0, 0, 0);
        xa[1] = __builtin_amdgcn_mfma_f32_16x16x32_bf16(x0, Wf[1][0], biasC[1], 0, 0, 0);
        xa[2] = __builtin_amdgcn_mfma_f32_16x16x32_bf16(x0, Wf[2][0], biasC[2], 0, 0, 0);
        xa[3] = __builtin_amdgcn_mfma_f32_16x16x32_bf16(x0, Wf[3][0], biasC[3], 0, 0, 0);
        xa[0] = __builtin_amdgcn_mfma_f32_16x16x32_bf16(x1, Wf[0][1], xa[0], 0, 0, 0);
        xa[1] = __builtin_amdgcn_mfma_f32_16x16x32_bf16(x1, Wf[1][1], xa[1], 0, 0, 0);
        xa[2] = __builtin_amdgcn_mfma_f32_16x16x32_bf16(x1, Wf[2][1], xa[2], 0, 0, 0);
        xa[3] = __builtin_amdgcn_mfma_f32_16x16x32_bf16(x1, Wf[3][1], xa[3], 0, 0, 0);

        if (s + 4 < T) {
            const unsigned short* pn = hl + (size_t)(d ? (T - 5 - s) : (s + 4)) * 1024;
            x0 = *(const bf16x8*)(pn); x1 = *(const bf16x8*)(pn + 512);
        }

        // wave-uniform row select (sh in SGPR -> uniform branch)
        float z0, z1, z2, z3;
        if (sh == 0)      { z0 = a0[0]; z1 = a1[0]; z2 = a2[0]; z3 = a3[0]; }
        else if (sh == 1) { z0 = a0[1]; z1 = a1[1]; z2 = a2[1]; z3 = a3[1]; }
        else if (sh == 2) { z0 = a0[2]; z1 = a1[2]; z2 = a2[2]; z3 = a3[2]; }
        else              { z0 = a0[3]; z1 = a1[3]; z2 = a2[3]; z3 = a3[3]; }
        const float ig = sigmoidf_(z0);
        const float fg = sigmoidf_(z1);
        const float gg = tanhf_(z2);
        const float og = sigmoidf_(z3);
        c = fg * c + ig * gg;
        hlast = og * tanhf_(c);
        hb2[d][(s + 1) & 1][(quad * 4 + sh) * 24 + n15] = f2bf(hlast);
        lds_barrier();
    };

    #pragma unroll 1
    for (int s = 0; s < T; s += 2) {
        step(s, xaA, hA0, hA1);
        step(s + 1, xaB, hB0, hB1);
    }

    hfin[d][quad * 4 + sh][n15] = hlast;
    __syncthreads();

    if (tid < 128) {
        const int s = tid >> 3, u = tid & 7;      // 16 samples x 8 units
        float a = b3[u];
        #pragma unroll
        for (int k = 0; k < H2; ++k) a += hfin[0][s][k] * W3[k * 8 + u];
        #pragma unroll
        for (int k = 0; k < H2; ++k) a += hfin[1][s][k] * W3[(H2 + k) * 8 + u];
        ybuf[s][u] = a * sigmoidf_(a);
    }
    __syncthreads();
    if (tid < 32) {
        const int s = tid >> 1, o = tid & 1;
        float a = b4[o];
        #pragma unroll
        for (int k = 0; k < 8; ++k) a += ybuf[s][k] * W4[k * 2 + o];
        out[(size_t)(g * 16 + s) * 2 + o] = sigmoidf_(a);
    }
}

extern "C" void kernel_launch(void* const* d_in, const int* in_sizes, int n_in,
                              void* d_out, int out_size, void* d_ws, size_t ws_size,
                              hipStream_t stream) {
    const float* x   = (const float*)d_in[0];
    const float* W1f = (const float*)d_in[1];
    const float* U1f = (const float*)d_in[2];
    const float* b1f = (const float*)d_in[3];
    const float* W1b = (const float*)d_in[4];
    const float* U1b = (const float*)d_in[5];
    const float* b1b = (const float*)d_in[6];
    const float* W2f = (const float*)d_in[7];
    const float* U2f = (const float*)d_in[8];
    const float* b2f = (const float*)d_in[9];
    const float* W2b = (const float*)d_in[10];
    const float* U2b = (const float*)d_in[11];
    const float* b2b = (const float*)d_in[12];
    const float* W3  = (const float*)d_in[13];
    const float* b3  = (const float*)d_in[14];
    const float* W4  = (const float*)d_in[15];
    const float* b4  = (const float*)d_in[16];
    float* out = (float*)d_out;

    const int B  = in_sizes[0] / (T * F);
    const int NG = B / 16;                       // sample groups

    // ws: xbf (256 KB/group) + h1 (256 KB/group), chunked if ws is small
    const size_t perG = (size_t)T * 1024 * sizeof(unsigned short);  // 256 KB
    int chG = (int)(ws_size / (2 * perG));
    if (chG > NG) chG = NG;
    if (chG < 1) chG = 1;
    unsigned short* xbf = (unsigned short*)d_ws;
    unsigned short* h1  = xbf + (size_t)chG * T * 1024;

    for (int g0 = 0; g0 < NG; g0 += chG) {
        const int cg = (NG - g0 < chG) ? (NG - g0) : chG;
        dim3 gcv(cg, T / 8);
        xcvt<<<gcv, 256, 0, stream>>>(x + (size_t)g0 * 16 * T * F, xbf);
        lstm1_fused<<<cg * 2, 256, 0, stream>>>(
            xbf, W1f, b1f, U1f, W1b, b1b, U1b, h1);
        lstm2_head<<<cg, 512, 0, stream>>>(
            h1, W2f, b2f, U2f, W2b, b2b, U2b, W3, b3, W4, b4,
            out + (size_t)g0 * 16 * 2);
    }
}